// Round 1
// baseline (51.848 us; speedup 1.0000x reference)
//
#include <hip/hip_runtime.h>

#define WORKERS 2048
#define TASKS   2048
#define ETYPE   16
#define ABIL    64

// Exponent totals per worker row: TASKS*ETYPE = 32768 floats of output.
#define PER_WORKER (TASKS * ETYPE)        // 32768
#define PER_WORKER4 (PER_WORKER / 4)      // 8192
#define TOTAL4 (WORKERS * TASKS * ETYPE / 4)  // 16,777,216

// ---------------------------------------------------------------------------
// Kernel 1: per-worker l1 = log2(p1), l2 = log2(p2); compact tau slice.
//   p1 = sigmoid(feature . W + b), p2 = (1-p1)/15
// Launch: 32 blocks x 256 = 8192 threads.
//   threads 0..2047  : worker computation
//   threads 0..8191  : copy one float4 of tau (strided rows -> contiguous)
// ---------------------------------------------------------------------------
__global__ void prep_kernel(const float* __restrict__ inputs,
                            const float* __restrict__ W,
                            const float* __restrict__ b,
                            float* __restrict__ l1,
                            float* __restrict__ l2,
                            float* __restrict__ tauc) {
    const int tid = blockIdx.x * blockDim.x + threadIdx.x;

    if (tid < WORKERS) {
        const float4* row = reinterpret_cast<const float4*>(inputs + (size_t)tid * ABIL);
        const float4* Wv  = reinterpret_cast<const float4*>(W);
        float acc = 0.0f;
#pragma unroll
        for (int k = 0; k < ABIL / 4; ++k) {
            float4 x = row[k];
            float4 w = Wv[k];
            acc = fmaf(x.x, w.x, acc);
            acc = fmaf(x.y, w.y, acc);
            acc = fmaf(x.z, w.z, acc);
            acc = fmaf(x.w, w.w, acc);
        }
        acc += b[0];
        // sigmoid(acc) = 1 / (1 + exp(-acc)); exp(-x) = exp2(-x * log2(e))
        const float LOG2E = 1.4426950408889634f;
        float e = __builtin_amdgcn_exp2f(-acc * LOG2E);
        float p1 = 1.0f / (1.0f + e);
        float p2 = (1.0f - p1) * (1.0f / (ETYPE - 1));
        // v_log_f32(0) = -inf -> exp2 path yields exact 0, matching reference.
        l1[tid] = __builtin_amdgcn_logf(p1);
        l2[tid] = __builtin_amdgcn_logf(p2);
    }

    // tau copy: tau[t][e] = inputs[(WORKERS + t)*ABIL + e], e in [0,16)
    // float4 chunk j: t = j>>2, e0 = (j&3)*4
    if (tid < PER_WORKER4) {
        int t  = tid >> 2;
        int e0 = (tid & 3) * 4;
        const float4* src = reinterpret_cast<const float4*>(
            inputs + (size_t)(WORKERS + t) * ABIL + e0);
        reinterpret_cast<float4*>(tauc)[tid] = *src;
    }
}

// ---------------------------------------------------------------------------
// Kernel 2: P[w][t][e] = exp2( tau*l1[w] + (1-tau)*l2[w] )
// Grid-stride over float4 outputs; coalesced 16B stores.
// ---------------------------------------------------------------------------
__global__ void __launch_bounds__(256)
pow_kernel(const float* __restrict__ l1,
           const float* __restrict__ l2,
           const float* __restrict__ tauc,
           float4* __restrict__ out) {
    const int stride = gridDim.x * blockDim.x;
    for (int i = blockIdx.x * blockDim.x + threadIdx.x; i < TOTAL4; i += stride) {
        const int w    = i >> 13;                 // i / 8192 (float4s per worker)
        const int rem4 = i & (PER_WORKER4 - 1);   // float4 index into tauc
        const float4 tau = reinterpret_cast<const float4*>(tauc)[rem4];
        const float a = l1[w];   // wave-uniform except at worker boundaries
        const float c = l2[w];
        float4 r;
        // Two-term form: if c = -inf (p1 saturated to 1), finite + (-inf) = -inf
        // -> exp2 = 0 (matches reference); factored form would produce NaN.
        r.x = __builtin_amdgcn_exp2f(fmaf(tau.x, a, (1.0f - tau.x) * c));
        r.y = __builtin_amdgcn_exp2f(fmaf(tau.y, a, (1.0f - tau.y) * c));
        r.z = __builtin_amdgcn_exp2f(fmaf(tau.z, a, (1.0f - tau.z) * c));
        r.w = __builtin_amdgcn_exp2f(fmaf(tau.w, a, (1.0f - tau.w) * c));
        out[i] = r;
    }
}

extern "C" void kernel_launch(void* const* d_in, const int* in_sizes, int n_in,
                              void* d_out, int out_size, void* d_ws, size_t ws_size,
                              hipStream_t stream) {
    const float* inputs = (const float*)d_in[0];
    const float* W      = (const float*)d_in[1];
    const float* b      = (const float*)d_in[2];

    float* ws   = (float*)d_ws;
    float* l1   = ws;                  // 2048 floats
    float* l2   = ws + WORKERS;        // 2048 floats
    float* tauc = ws + 2 * WORKERS;    // 32768 floats (16 KiB offset -> aligned)

    prep_kernel<<<32, 256, 0, stream>>>(inputs, W, b, l1, l2, tauc);

    const int blocks = 2048;           // grid-stride; ~8 blocks/CU territory
    pow_kernel<<<blocks, 256, 0, stream>>>(l1, l2, tauc, (float4*)d_out);
}

// Round 2
// 46.310 us; speedup vs baseline: 1.1196x; 1.1196x over previous
//
#include <hip/hip_runtime.h>

#define WORKERS 2048
#define TASKS   2048
#define ETYPE   16
#define ABIL    64

#define F4_PER_WORKER  8192               // 32768 floats per worker / 4
#define F4_PER_BLOCK   4096               // half a worker per block
#define ITERS          16                 // 4096 f4 / 256 threads

// ---------------------------------------------------------------------------
// Single fused kernel.
// Block b owns float4 span [b*4096, (b+1)*4096) of out -> worker w = b>>1
// (block-uniform). Every thread redundantly computes the worker's
// l1=log2(p1), l2=log2(p2) (block-uniform addresses -> scalar/L1-broadcast
// loads, ~64 FMA + 2 transcendentals: negligible vs. the write budget), then
// streams 16 lane-contiguous float4 stores.
//   P[w][t][e] = exp2( tau[t][e]*l1 + (1-tau[t][e])*l2 )
// Two-term exponent form keeps the p1==1 -> l2=-inf case producing exact 0
// (matches reference) instead of NaN.
// ---------------------------------------------------------------------------
__global__ void __launch_bounds__(256)
fused_kernel(const float* __restrict__ inputs,
             const float* __restrict__ W,
             const float* __restrict__ b,
             float4* __restrict__ out) {
    const int blk  = blockIdx.x;
    const int w    = blk >> 1;            // worker index, block-uniform
    const int half = blk & 1;

    // --- per-worker scalars (redundant per thread, block-uniform) ---
    const float4* row = reinterpret_cast<const float4*>(inputs + (size_t)w * ABIL);
    const float4* Wv  = reinterpret_cast<const float4*>(W);
    float acc = 0.0f;
#pragma unroll
    for (int k = 0; k < ABIL / 4; ++k) {
        float4 x  = row[k];
        float4 wv = Wv[k];
        acc = fmaf(x.x, wv.x, acc);
        acc = fmaf(x.y, wv.y, acc);
        acc = fmaf(x.z, wv.z, acc);
        acc = fmaf(x.w, wv.w, acc);
    }
    acc += b[0];
    const float LOG2E = 1.4426950408889634f;
    float e  = __builtin_amdgcn_exp2f(-acc * LOG2E);
    float p1 = 1.0f / (1.0f + e);
    float p2 = (1.0f - p1) * (1.0f / (ETYPE - 1));
    const float a = __builtin_amdgcn_logf(p1);   // v_log_f32 = log2
    const float c = __builtin_amdgcn_logf(p2);

    // --- stream 16 float4 outputs, lane-contiguous per instruction ---
    const int base = w * F4_PER_WORKER + half * F4_PER_BLOCK + (int)threadIdx.x;
#pragma unroll
    for (int it = 0; it < ITERS; ++it) {
        const int i    = base + it * 256;
        const int rem4 = i & (F4_PER_WORKER - 1);     // f4 index within worker
        const int t    = rem4 >> 2;                   // task index
        const int e0   = (rem4 & 3) * 4;              // edge-type offset
        const float4 tau = *reinterpret_cast<const float4*>(
            inputs + (size_t)(WORKERS + t) * ABIL + e0);   // L2-resident
        float4 r;
        r.x = __builtin_amdgcn_exp2f(fmaf(tau.x, a, (1.0f - tau.x) * c));
        r.y = __builtin_amdgcn_exp2f(fmaf(tau.y, a, (1.0f - tau.y) * c));
        r.z = __builtin_amdgcn_exp2f(fmaf(tau.z, a, (1.0f - tau.z) * c));
        r.w = __builtin_amdgcn_exp2f(fmaf(tau.w, a, (1.0f - tau.w) * c));
        out[i] = r;
    }
}

extern "C" void kernel_launch(void* const* d_in, const int* in_sizes, int n_in,
                              void* d_out, int out_size, void* d_ws, size_t ws_size,
                              hipStream_t stream) {
    const float* inputs = (const float*)d_in[0];
    const float* W      = (const float*)d_in[1];
    const float* b      = (const float*)d_in[2];

    const int blocks = WORKERS * 2;       // 4096 blocks x 256 threads
    fused_kernel<<<blocks, 256, 0, stream>>>(inputs, W, b, (float4*)d_out);
}